// Round 1
// baseline (194.131 us; speedup 1.0000x reference)
//
#include <hip/hip_runtime.h>
#include <stdint.h>

#define BN 4096
#define DD 128
#define EPSF 1e-6f
#define MARGINF 1.0f

typedef unsigned long long ull;
typedef unsigned short ushort;
typedef short short8 __attribute__((ext_vector_type(8)));
typedef float f32x4 __attribute__((ext_vector_type(4)));

__device__ __forceinline__ unsigned int ord_f32(float f) {
    unsigned int u = __float_as_uint(f);
    return (u & 0x80000000u) ? ~u : (u | 0x80000000u);
}
__device__ __forceinline__ ushort bf16_rne(float x) {
    unsigned int u = __float_as_uint(x);
    return (ushort)((u + 0x7FFFu + ((u >> 16) & 1u)) >> 16);
}

// --- prep: row stats + inv perm + key init + bf16 convert of e ---
__global__ void k_prep(const float* __restrict__ e, const int* __restrict__ tidx,
                       float* __restrict__ sq, float* __restrict__ s,
                       int* __restrict__ inv, ull* __restrict__ pk, ull* __restrict__ nk,
                       unsigned int* __restrict__ ehi, unsigned int* __restrict__ cnt) {
    int w = threadIdx.x >> 6, lane = threadIdx.x & 63;
    int row = blockIdx.x * 4 + w;
    if (blockIdx.x == 0 && threadIdx.x == 0) cnt[0] = 0u;   // last-block counter
    float2 v = ((const float2*)(e + (size_t)row * DD))[lane];
    ushort hx = bf16_rne(v.x), hy = bf16_rne(v.y);
    ehi[row * 64 + lane] = (unsigned int)hx | ((unsigned int)hy << 16);
    float ss = v.x + v.y;
    float qq = v.x * v.x + v.y * v.y;
    #pragma unroll
    for (int off = 32; off > 0; off >>= 1) {
        ss += __shfl_down(ss, off);
        qq += __shfl_down(qq, off);
    }
    if (lane == 0) {
        sq[row] = qq; s[row] = ss;
        inv[tidx[row]] = row;
        pk[row] = 0ULL; nk[row] = 0ULL;   // both max-merged (neg uses inverted keys)
    }
}

// --- fused: bf16 MFMA + per-lane mask loads + selection; 128x128 tile ---
// Key idea: acc[rt][ct][t] lives at (row = wr*64+rt*16+quad*4+t, col = wc*64+ct*16+lrow)
// for lane (quad,lrow). Loading the mask dword at exactly that (row,col) puts the
// needed bit in the owning lane: no LDS staging, no pack, no cross-lane moves.
__global__ __launch_bounds__(256, 4)
void k_select(const ushort* __restrict__ ehi,
              const int* __restrict__ pos, const int* __restrict__ neg,
              const float* __restrict__ sq, const float* __restrict__ s,
              const int* __restrict__ inv,
              ull* __restrict__ pkey, ull* __restrict__ nkey) {
    // smem phases:
    //  phase A: B staging [2 kc][128 r][72] ushorts = 36864 B
    //  phase B (realias): scrp [128][17] ull = 17408 B, scrn [128][17] ull = 17408 B
    __shared__ __align__(16) char smem[36864];
    __shared__ float rjl[128];
    __shared__ int jvs[128];

    const int tid = threadIdx.x;
    const int lane = tid & 63;
    const int w = tid >> 6, wr = w >> 1, wc = w & 1;
    const int lrow = lane & 15, quad = lane >> 4;
    const int i0 = blockIdx.x * 128, c0 = blockIdx.y * 128;

    if (tid < 128) {
        int j = inv[c0 + tid];
        jvs[tid] = j;
        rjl[tid] = sq[j] - 2.0f * EPSF * s[j];
    }
    __syncthreads();

    // stage B (gathered rows) once for all K
    ushort* Bst = (ushort*)smem;
    #pragma unroll
    for (int it = 0; it < 8; it++) {
        int slot = it * 256 + tid;
        int r = slot >> 4, seg16 = slot & 15;
        int kc = seg16 >> 3, seg = seg16 & 7;
        int jr = jvs[r];
        int4 v = ((const int4*)ehi)[(size_t)jr * 16 + seg16];
        *(int4*)(Bst + (kc * 128 + r) * 72 + seg * 8) = v;
    }
    __syncthreads();

    f32x4 acc[4][4];
    #pragma unroll
    for (int rt = 0; rt < 4; rt++)
        #pragma unroll
        for (int ct = 0; ct < 4; ct++)
            acc[rt][ct] = (f32x4){0.f, 0.f, 0.f, 0.f};

    size_t abase[4];
    #pragma unroll
    for (int rt = 0; rt < 4; rt++)
        abase[rt] = (size_t)(i0 + wr * 64 + rt * 16 + lrow) * DD + quad * 8;

    // K-loop: no barriers; A direct from global (L2-resident), B from LDS
    #pragma unroll
    for (int ks = 0; ks < 4; ks++) {
        const int kc = ks >> 1, ksl = ks & 1;
        short8 ah[4];
        #pragma unroll
        for (int rt = 0; rt < 4; rt++)
            ah[rt] = *(const short8*)(ehi + abase[rt] + ks * 32);
        #pragma unroll
        for (int ct = 0; ct < 4; ct++) {
            const int bo = (kc * 128 + wc * 64 + ct * 16 + lrow) * 72 + ksl * 32 + quad * 8;
            short8 bh = *(const short8*)(Bst + bo);
            #pragma unroll
            for (int rt = 0; rt < 4; rt++)
                acc[rt][ct] = __builtin_amdgcn_mfma_f32_16x16x32_bf16(ah[rt], bh, acc[rt][ct], 0, 0, 0);
        }
    }

    __syncthreads();   // B reads done; realias smem as selection scratch

    ull* scrp = (ull*)smem;                  // [128][17] (pad 17: writes <=2-way banked)
    ull* scrn = (ull*)(smem + 17408);        // [128][17]

    unsigned int jninv[4]; float rjc[4];
    #pragma unroll
    for (int ct = 0; ct < 4; ct++) {
        int cc = wc * 64 + ct * 16 + lrow;
        jninv[ct] = 0xFFFFFFFFu - (unsigned int)jvs[cc];
        rjc[ct] = rjl[cc];
    }

    // mask address: this lane's own (row, col) elements
    const size_t mrow0 = (size_t)(i0 + wr * 64 + quad * 4) * BN + (size_t)(c0 + wc * 64 + lrow);
    const int rbase = wr * 64 + quad * 4;

    // selection on m = rj - 2*dot (row-constant terms dropped; per-row order identical)
    #pragma unroll
    for (int rt = 0; rt < 4; rt++) {
        #pragma unroll
        for (int t = 0; t < 4; t++) {
            const size_t mb = mrow0 + (size_t)(rt * 16 + t) * BN;
            int pd[4], nd[4];
            #pragma unroll
            for (int ct = 0; ct < 4; ct++) {
                pd[ct] = pos[mb + ct * 16];
                nd[ct] = neg[mb + ct * 16];
            }
            ull kp = 0ULL, kn = 0ULL;
            #pragma unroll
            for (int ct = 0; ct < 4; ct++) {
                float m = rjc[ct] - 2.0f * acc[rt][ct][t];
                unsigned int om = ord_f32(m);
                ull keyp = ((ull)om << 32) | (ull)jninv[ct];
                ull keyn = ((ull)(om ^ 0xFFFFFFFFu) << 32) | (ull)jninv[ct];
                if (pd[ct] != 0 && keyp > kp) kp = keyp;   // max-m, ties -> smaller j
                if (nd[ct] != 0 && keyn > kn) kn = keyn;   // min-m, ties -> smaller j
            }
            ull op = __shfl_xor(kp, 8); if (op > kp) kp = op;   // fold lrow with lrow^8
            ull on = __shfl_xor(kn, 8); if (on > kn) kn = on;
            if (lrow < 8) {
                const int row = rbase + rt * 16 + t;
                scrp[row * 17 + wc * 8 + lrow] = kp;
                scrn[row * 17 + wc * 8 + lrow] = kn;
            }
        }
    }
    __syncthreads();
    if (tid < 128) {
        ull kp = 0ULL, kn = 0ULL;
        #pragma unroll
        for (int k = 0; k < 16; k++) {
            ull v = scrp[tid * 17 + k]; if (v > kp) kp = v;
            v = scrn[tid * 17 + k];     if (v > kn) kn = v;
        }
        if (kp) atomicMax(&pkey[i0 + tid], kp);
        if (kn) atomicMax(&nkey[i0 + tid], kn);
    }
}

// --- per-row triplet loss + last-block finalize (deterministic reduce order) ---
__global__ void k_loss(const float* __restrict__ e,
                       const ull* __restrict__ pkey, const ull* __restrict__ nkey,
                       float* __restrict__ partials, unsigned int* __restrict__ cnt,
                       float* __restrict__ out) {
    int w = threadIdx.x >> 6, lane = threadIdx.x & 63;
    int row = blockIdx.x * 4 + w;
    ull pk = pkey[row], nk = nkey[row];
    float loss = 0.0f, wt = 0.0f;
    if (pk != 0ULL && nk != 0ULL) {
        int pi = (int)(0xFFFFFFFFu - (unsigned)(pk & 0xFFFFFFFFu));
        int ni = (int)(0xFFFFFFFFu - (unsigned)(nk & 0xFFFFFFFFu));
        float2 av = ((const float2*)(e + (size_t)row * DD))[lane];
        float2 pv = ((const float2*)(e + (size_t)pi * DD))[lane];
        float2 nv = ((const float2*)(e + (size_t)ni * DD))[lane];
        float dx, dy;
        dx = av.x - pv.x + EPSF; dy = av.y - pv.y + EPSF;
        float ap2 = dx * dx + dy * dy;
        dx = av.x - nv.x + EPSF; dy = av.y - nv.y + EPSF;
        float an2 = dx * dx + dy * dy;
        dx = pv.x - nv.x + EPSF; dy = pv.y - nv.y + EPSF;
        float pn2 = dx * dx + dy * dy;
        #pragma unroll
        for (int off = 32; off > 0; off >>= 1) {
            ap2 += __shfl_down(ap2, off);
            an2 += __shfl_down(an2, off);
            pn2 += __shfl_down(pn2, off);
        }
        if (lane == 0) {
            float ap = sqrtf(ap2), an = sqrtf(an2), pn = sqrtf(pn2);
            loss = fmaxf(ap - fminf(an, pn) + MARGINF, 0.0f);
            wt = 1.0f;
        }
    }
    __shared__ float sl[4], sw[4];
    __shared__ unsigned int rank;
    if (lane == 0) { sl[w] = loss; sw[w] = wt; }
    __syncthreads();
    if (threadIdx.x == 0) {
        float L = sl[0] + sl[1] + sl[2] + sl[3];
        float W = sw[0] + sw[1] + sw[2] + sw[3];
        // agent-scope stores bypass the (non-coherent) per-XCD L2
        __hip_atomic_store(&partials[blockIdx.x * 2 + 0], L, __ATOMIC_RELAXED, __HIP_MEMORY_SCOPE_AGENT);
        __hip_atomic_store(&partials[blockIdx.x * 2 + 1], W, __ATOMIC_RELAXED, __HIP_MEMORY_SCOPE_AGENT);
        __threadfence();
        rank = atomicAdd(cnt, 1u);
    }
    __syncthreads();
    if (rank == (unsigned)(gridDim.x - 1)) {   // last block finalizes (fixed order)
        __threadfence();
        int tid = threadIdx.x;
        float L = 0.0f, W = 0.0f;
        #pragma unroll
        for (int i = 0; i < 4; i++) {
            int idx = tid + i * 256;
            L += __hip_atomic_load(&partials[idx * 2 + 0], __ATOMIC_RELAXED, __HIP_MEMORY_SCOPE_AGENT);
            W += __hip_atomic_load(&partials[idx * 2 + 1], __ATOMIC_RELAXED, __HIP_MEMORY_SCOPE_AGENT);
        }
        #pragma unroll
        for (int off = 32; off > 0; off >>= 1) {
            L += __shfl_down(L, off);
            W += __shfl_down(W, off);
        }
        __shared__ float fl[4], fw[4];
        int w2 = tid >> 6, l2 = tid & 63;
        if (l2 == 0) { fl[w2] = L; fw[w2] = W; }
        __syncthreads();
        if (tid == 0) {
            float Lt = fl[0] + fl[1] + fl[2] + fl[3];
            float Wt = fw[0] + fw[1] + fw[2] + fw[3];
            out[0] = Lt / fmaxf(Wt, 1.0f);
        }
    }
}

extern "C" void kernel_launch(void* const* d_in, const int* in_sizes, int n_in,
                              void* d_out, int out_size, void* d_ws, size_t ws_size,
                              hipStream_t stream) {
    const float* e    = (const float*)d_in[0];
    const int*   tidx = (const int*)d_in[1];
    const int*   pos  = (const int*)d_in[2];
    const int*   neg  = (const int*)d_in[3];
    float* out = (float*)d_out;

    ull* pkey  = (ull*)d_ws;                  // 4096
    ull* nkey  = pkey + BN;                   // 4096
    float* sq  = (float*)(nkey + BN);
    float* s   = sq + BN;
    int* inv   = (int*)(s + BN);
    float* partials = (float*)(inv + BN);     // 2048
    unsigned int* ehi = (unsigned int*)(partials + 2048);  // 4096*64 uints
    unsigned int* cnt = ehi + (size_t)BN * 64;

    k_prep<<<BN / 4, 256, 0, stream>>>(e, tidx, sq, s, inv, pkey, nkey, ehi, cnt);
    dim3 grid(BN / 128, BN / 128);
    k_select<<<grid, 256, 0, stream>>>((const ushort*)ehi, pos, neg,
                                       sq, s, inv, pkey, nkey);
    k_loss<<<BN / 4, 256, 0, stream>>>(e, pkey, nkey, partials, cnt, out);
}

// Round 2
// 181.596 us; speedup vs baseline: 1.0690x; 1.0690x over previous
//
#include <hip/hip_runtime.h>
#include <stdint.h>

#define BN 4096
#define DD 128
#define EPSF 1e-6f
#define MARGINF 1.0f

typedef unsigned long long ull;
typedef unsigned short ushort;
typedef short short8 __attribute__((ext_vector_type(8)));
typedef float f32x4 __attribute__((ext_vector_type(4)));

__device__ __forceinline__ unsigned int ord_f32(float f) {
    unsigned int u = __float_as_uint(f);
    return (u & 0x80000000u) ? ~u : (u | 0x80000000u);
}
__device__ __forceinline__ ushort bf16_rne(float x) {
    unsigned int u = __float_as_uint(x);
    return (ushort)((u + 0x7FFFu + ((u >> 16) & 1u)) >> 16);
}

// --- prep: per-row stats -> per-COLUMN tables (rjp, jn), inv perm, key init,
//     bf16 convert of e ---
__global__ void k_prep(const float* __restrict__ e, const int* __restrict__ tidx,
                       int* __restrict__ inv, float* __restrict__ rjp,
                       unsigned int* __restrict__ jn,
                       ull* __restrict__ pk, ull* __restrict__ nk,
                       unsigned int* __restrict__ ehi) {
    int w = threadIdx.x >> 6, lane = threadIdx.x & 63;
    int row = blockIdx.x * 4 + w;
    float2 v = ((const float2*)(e + (size_t)row * DD))[lane];
    ushort hx = bf16_rne(v.x), hy = bf16_rne(v.y);
    ehi[row * 64 + lane] = (unsigned int)hx | ((unsigned int)hy << 16);
    float ss = v.x + v.y;
    float qq = v.x * v.x + v.y * v.y;
    #pragma unroll
    for (int off = 32; off > 0; off >>= 1) {
        ss += __shfl_down(ss, off);
        qq += __shfl_down(qq, off);
    }
    if (lane == 0) {
        int c = tidx[row];
        inv[c] = row;
        rjp[c] = qq - 2.0f * EPSF * ss;        // same arithmetic as before
        jn[c] = 0xFFFFFFFFu - (unsigned int)row;
        pk[row] = 0ULL; nk[row] = 0ULL;        // both max-merged (neg uses inverted keys)
    }
}

// --- fused MFMA + selection; block = 16 rows x 1024 cols ---
// Rationale: mask reads are the dominant (mandatory) HBM stream. A wide flat
// tile walks each mask row SEQUENTIALLY (4 KB runs) instead of isolated 512 B
// chunks at 16 KB stride -> DRAM row-buffer efficiency. A-frags load once per
// block; B-frags stream from L2-hot ehi; no barriers in the main loop.
__global__ __launch_bounds__(256, 4)
void k_select(const ushort* __restrict__ ehi,
              const int* __restrict__ pos, const int* __restrict__ neg,
              const int* __restrict__ inv, const float* __restrict__ rjp,
              const unsigned int* __restrict__ jn,
              ull* __restrict__ pkey, ull* __restrict__ nkey) {
    __shared__ int jvsL[1024];
    __shared__ float rjL[1024];
    __shared__ unsigned int jnL[1024];
    __shared__ ull scrp[16 * 4], scrn[16 * 4];

    const int tid = threadIdx.x;
    const int lane = tid & 63, w = tid >> 6;
    const int lrow = lane & 15, quad = lane >> 4;
    const int r0 = blockIdx.x * 16;
    const int c0 = blockIdx.y * 1024;

    // stage per-column tables once (columns c0..c0+1023)
    #pragma unroll
    for (int k = 0; k < 4; k++) {
        int idx = k * 256 + tid;
        jvsL[idx] = inv[c0 + idx];
        rjL[idx]  = rjp[c0 + idx];
        jnL[idx]  = jn[c0 + idx];
    }

    // A fragments: 16 rows, loaded ONCE, reused for all 16 column tiles
    short8 a[4];
    #pragma unroll
    for (int ks = 0; ks < 4; ks++)
        a[ks] = *(const short8*)(ehi + (size_t)(r0 + lrow) * DD + ks * 32 + quad * 8);

    __syncthreads();

    ull kp[4] = {0ULL, 0ULL, 0ULL, 0ULL};
    ull kn[4] = {0ULL, 0ULL, 0ULL, 0ULL};

    // double-buffered prefetch state (one 64-col tile ahead)
    int pm[2][4], nm[2][4];
    short8 bf[2][4];
    float rjc[2]; unsigned int jni[2];

#define LOADTILE(BUF, JT) do {                                                 \
        const int lcol = (JT) * 64 + w * 16 + lrow;                            \
        const int jr = jvsL[lcol];                                             \
        rjc[BUF] = rjL[lcol];                                                  \
        jni[BUF] = jnL[lcol];                                                  \
        const int* pp = pos + (size_t)(r0 + quad * 4) * BN + (size_t)(c0 + lcol); \
        const int* np = neg + (size_t)(r0 + quad * 4) * BN + (size_t)(c0 + lcol); \
        _Pragma("unroll")                                                      \
        for (int t = 0; t < 4; t++) {                                          \
            pm[BUF][t] = pp[(size_t)t * BN];                                   \
            nm[BUF][t] = np[(size_t)t * BN];                                   \
        }                                                                      \
        const ushort* bp = ehi + (size_t)jr * DD + quad * 8;                   \
        _Pragma("unroll")                                                      \
        for (int ks = 0; ks < 4; ks++)                                         \
            bf[BUF][ks] = *(const short8*)(bp + ks * 32);                      \
    } while (0)

    LOADTILE(0, 0);

    #pragma unroll
    for (int jt = 0; jt < 16; jt++) {
        const int cur = jt & 1, nxt = cur ^ 1;
        if (jt < 15) {
            if (nxt == 0) LOADTILE(0, jt + 1); else LOADTILE(1, jt + 1);
        }
        f32x4 acc = (f32x4){0.f, 0.f, 0.f, 0.f};
        #pragma unroll
        for (int ks = 0; ks < 4; ks++)
            acc = __builtin_amdgcn_mfma_f32_16x16x32_bf16(a[ks], bf[cur][ks], acc, 0, 0, 0);
        // selection on m = rj - 2*dot (row-constant terms dropped)
        #pragma unroll
        for (int t = 0; t < 4; t++) {
            float m = rjc[cur] - 2.0f * acc[t];
            unsigned int om = ord_f32(m);
            ull keyp = ((ull)om << 32) | (ull)jni[cur];
            ull keyn = ((ull)(om ^ 0xFFFFFFFFu) << 32) | (ull)jni[cur];
            if (pm[cur][t] != 0 && keyp > kp[t]) kp[t] = keyp;   // max-m, ties -> smaller j
            if (nm[cur][t] != 0 && keyn > kn[t]) kn[t] = keyn;   // min-m, ties -> smaller j
        }
    }
#undef LOADTILE

    // fold across the 16 lanes of each quad (all hold same rows, different cols)
    #pragma unroll
    for (int t = 0; t < 4; t++) {
        #pragma unroll
        for (int off = 8; off > 0; off >>= 1) {
            ull o = __shfl_xor(kp[t], off); if (o > kp[t]) kp[t] = o;
            o = __shfl_xor(kn[t], off);     if (o > kn[t]) kn[t] = o;
        }
        if (lrow == 0) {
            scrp[(quad * 4 + t) * 4 + w] = kp[t];
            scrn[(quad * 4 + t) * 4 + w] = kn[t];
        }
    }
    __syncthreads();
    if (tid < 16) {
        ull xp = 0ULL, xn = 0ULL;
        #pragma unroll
        for (int k = 0; k < 4; k++) {
            ull v = scrp[tid * 4 + k]; if (v > xp) xp = v;
            v = scrn[tid * 4 + k];     if (v > xn) xn = v;
        }
        if (xp) atomicMax(&pkey[r0 + tid], xp);
        if (xn) atomicMax(&nkey[r0 + tid], xn);
    }
}

// --- per-row triplet loss: wave per row (coalesced), block partials ---
__global__ void k_loss(const float* __restrict__ e,
                       const ull* __restrict__ pkey, const ull* __restrict__ nkey,
                       float* __restrict__ partials) {
    int w = threadIdx.x >> 6, lane = threadIdx.x & 63;
    int row = blockIdx.x * 4 + w;
    ull pk = pkey[row], nk = nkey[row];
    float loss = 0.0f, wt = 0.0f;
    if (pk != 0ULL && nk != 0ULL) {
        int pi = (int)(0xFFFFFFFFu - (unsigned)(pk & 0xFFFFFFFFu));
        int ni = (int)(0xFFFFFFFFu - (unsigned)(nk & 0xFFFFFFFFu));
        float2 av = ((const float2*)(e + (size_t)row * DD))[lane];
        float2 pv = ((const float2*)(e + (size_t)pi * DD))[lane];
        float2 nv = ((const float2*)(e + (size_t)ni * DD))[lane];
        float dx, dy;
        dx = av.x - pv.x + EPSF; dy = av.y - pv.y + EPSF;
        float ap2 = dx * dx + dy * dy;
        dx = av.x - nv.x + EPSF; dy = av.y - nv.y + EPSF;
        float an2 = dx * dx + dy * dy;
        dx = pv.x - nv.x + EPSF; dy = pv.y - nv.y + EPSF;
        float pn2 = dx * dx + dy * dy;
        #pragma unroll
        for (int off = 32; off > 0; off >>= 1) {
            ap2 += __shfl_down(ap2, off);
            an2 += __shfl_down(an2, off);
            pn2 += __shfl_down(pn2, off);
        }
        if (lane == 0) {
            float ap = sqrtf(ap2), an = sqrtf(an2), pn = sqrtf(pn2);
            loss = fmaxf(ap - fminf(an, pn) + MARGINF, 0.0f);
            wt = 1.0f;
        }
    }
    __shared__ float sl[4], sw[4];
    if (lane == 0) { sl[w] = loss; sw[w] = wt; }
    __syncthreads();
    if (threadIdx.x == 0) {
        partials[blockIdx.x * 2 + 0] = sl[0] + sl[1] + sl[2] + sl[3];
        partials[blockIdx.x * 2 + 1] = sw[0] + sw[1] + sw[2] + sw[3];
    }
}

// --- finalize ---
__global__ void k_final(const float* __restrict__ partials, float* __restrict__ out) {
    int tid = threadIdx.x;
    float L = 0.0f, W = 0.0f;
    for (int i = 0; i < 4; i++) {
        int idx = tid + i * 256;
        L += partials[idx * 2];
        W += partials[idx * 2 + 1];
    }
    #pragma unroll
    for (int off = 32; off > 0; off >>= 1) {
        L += __shfl_down(L, off);
        W += __shfl_down(W, off);
    }
    __shared__ float sl[4], sw[4];
    int w = tid >> 6, lane = tid & 63;
    if (lane == 0) { sl[w] = L; sw[w] = W; }
    __syncthreads();
    if (tid == 0) {
        float Lt = sl[0] + sl[1] + sl[2] + sl[3];
        float Wt = sw[0] + sw[1] + sw[2] + sw[3];
        out[0] = Lt / fmaxf(Wt, 1.0f);
    }
}

extern "C" void kernel_launch(void* const* d_in, const int* in_sizes, int n_in,
                              void* d_out, int out_size, void* d_ws, size_t ws_size,
                              hipStream_t stream) {
    const float* e    = (const float*)d_in[0];
    const int*   tidx = (const int*)d_in[1];
    const int*   pos  = (const int*)d_in[2];
    const int*   neg  = (const int*)d_in[3];
    float* out = (float*)d_out;

    ull* pkey  = (ull*)d_ws;                          // 4096 ull
    ull* nkey  = pkey + BN;                           // 4096 ull
    int* inv   = (int*)(nkey + BN);                   // 4096 int
    float* rjp = (float*)(inv + BN);                  // 4096 f32
    unsigned int* jn = (unsigned int*)(rjp + BN);     // 4096 u32
    float* partials  = (float*)(jn + BN);             // 2048 f32
    unsigned int* ehi = (unsigned int*)(partials + 2048);  // 4096*64 u32

    k_prep<<<BN / 4, 256, 0, stream>>>(e, tidx, inv, rjp, jn, pkey, nkey, ehi);
    dim3 grid(BN / 16, 4);
    k_select<<<grid, 256, 0, stream>>>((const ushort*)ehi, pos, neg,
                                       inv, rjp, jn, pkey, nkey);
    k_loss<<<BN / 4, 256, 0, stream>>>(e, pkey, nkey, partials);
    k_final<<<1, 256, 0, stream>>>(partials, out);
}